// Round 1
// baseline (290.234 us; speedup 1.0000x reference)
//
#include <hip/hip_runtime.h>
#include <hip/hip_fp16.h>

#define TAU 0.07f
#define MARGIN 0.2f
#define NSPEC 64
#define BB 8192
#define DD 256
#define DD2 128  // DD/2

// ---------------- ws layout (bytes) ----------------
// zeroed region: [0, 66560)
//   0      float scalars[8]  [0]=triSum [1]=infoSum [2]=n_valid [3]=n_valid_i
//   32     int   counts[64]
//   288    int   offsets[64]
//   1024   float lseRow[B]      (atomic accum of sum_j exp(logit))
//   33792  float lseCol[B]
// unzeroed:
//   66560  float diag[B]
//   99328  int   posin[B]
//   132096 int   memberList[B]   (g -> original row)
//   164864 float Ts[64*256]
//   230400 float T[256]
//   231424 uint  Th2[128*8192]   (half2-packed, [d2][g] gathered-transposed text)
#define WS_SCALARS   0
#define WS_COUNTS    32
#define WS_OFFSETS   288
#define WS_LSEROW    1024
#define WS_LSECOL    33792
#define WS_DIAG      66560
#define WS_POSIN     99328
#define WS_MEMBER    132096
#define WS_TS        164864
#define WS_T         230400
#define WS_TH2       231424
#define WS_ZERO_BYTES 66560

typedef _Float16 half2v __attribute__((ext_vector_type(2)));

__device__ __forceinline__ float dot2h(unsigned int a, unsigned int b, float c) {
#if __has_builtin(__builtin_amdgcn_fdot2)
  return __builtin_amdgcn_fdot2(__builtin_bit_cast(half2v, a),
                                __builtin_bit_cast(half2v, b), c, false);
#else
  __half2 ha = *reinterpret_cast<const __half2*>(&a);
  __half2 hb = *reinterpret_cast<const __half2*>(&b);
  float2 fa = __half22float2(ha), fb = __half22float2(hb);
  return c + fa.x * fb.x + fa.y * fb.y;
#endif
}

__device__ __forceinline__ unsigned int pack_h2(float x, float y) {
  return (unsigned int)__half_as_ushort(__float2half(x)) |
         ((unsigned int)__half_as_ushort(__float2half(y)) << 16);
}

// ---- k1: species counts + intra-species position ----
__global__ void k1_count(const int* __restrict__ ids, int* counts, int* posin) {
  int i = blockIdx.x * blockDim.x + threadIdx.x;
  if (i < BB) {
    int s = ids[i];
    posin[i] = atomicAdd(&counts[s], 1);
  }
}

// ---- k1b: serial prefix over 64 counts + valid counts ----
__global__ void k1b_scan(const int* __restrict__ counts, int* offsets, float* scalars) {
  if (threadIdx.x == 0) {
    int off = 0, nv = 0, nvi = 0;
    for (int s = 0; s < NSPEC; ++s) {
      offsets[s] = off;
      int c = counts[s];
      off += c;
      if (c >= 2) nv++;
      if (c >= 2 && c <= BB - 1) nvi += c;  // rows with pos_cnt>0 && neg_cnt>0
    }
    scalars[2] = (float)nv;
    scalars[3] = (float)nvi;
  }
}

// ---- k1c: scatter member list (g -> row) ----
__global__ void k1c_scatter(const int* __restrict__ ids, const int* __restrict__ posin,
                            const int* __restrict__ offsets, int* memberList) {
  int i = blockIdx.x * blockDim.x + threadIdx.x;
  if (i < BB) memberList[offsets[ids[i]] + posin[i]] = i;
}

// ---- k2: per-species text sums Ts[s][d] ----
__global__ void k2_ts(const float* __restrict__ tx, const int* __restrict__ counts,
                      const int* __restrict__ offsets, const int* __restrict__ memberList,
                      float* Ts) {
  int s = blockIdx.x, d = threadIdx.x;
  int m = counts[s], g0 = offsets[s];
  float acc = 0.f;
  for (int k = 0; k < m; ++k) acc += tx[memberList[g0 + k] * DD + d];
  Ts[s * DD + d] = acc;
}

// ---- k2b: global text sum T[d] ----
__global__ void k2b_t(const float* __restrict__ Ts, float* T) {
  int d = threadIdx.x;
  float acc = 0.f;
  for (int s = 0; s < NSPEC; ++s) acc += Ts[s * DD + d];
  T[d] = acc;
}

// ---- ktr: gathered transpose of text into half2 [d2][g] layout ----
__global__ void ktr_transpose(const float* __restrict__ tx, const int* __restrict__ memberList,
                              unsigned int* __restrict__ Th2) {
  __shared__ unsigned int tile[64][129];  // +1 dword pad: conflict-free both phases
  int g0 = blockIdx.x * 64;
  int half = threadIdx.x >> 7;   // 0/1: two member rows per iteration
  int d2 = threadIdx.x & 127;
  for (int k = 0; k < 64; k += 2) {
    int kk = k + half;
    int row = memberList[g0 + kk];
    float2 v = *reinterpret_cast<const float2*>(tx + row * DD + 2 * d2);
    tile[kk][d2] = pack_h2(v.x, v.y);
  }
  __syncthreads();
  for (int it = 0; it < 32; ++it) {
    int flat = it * 256 + threadIdx.x;
    int dd = flat >> 6;    // 0..127
    int g = flat & 63;
    Th2[dd * BB + g0 + g] = tile[g][dd];  // coalesced 256B per wave
  }
}

// ---- k4: diag, row_sum, row_same_sum -> triplet accumulation; writes diag ----
__global__ void k4_rows(const float* __restrict__ sp, const float* __restrict__ tx,
                        const int* __restrict__ ids, const int* __restrict__ counts,
                        const float* __restrict__ Ts, const float* __restrict__ T,
                        float* diag, float* scalars) {
  int tid = blockIdx.x * blockDim.x + threadIdx.x;
  int w = tid >> 6, lane = tid & 63;
  const int NW = (256 * 256) >> 6;  // 1024 waves
  float4 tv = *reinterpret_cast<const float4*>(T + lane * 4);
  float triAcc = 0.f;
  for (int i = w; i < BB; i += NW) {
    float4 a = *reinterpret_cast<const float4*>(sp + i * DD + lane * 4);
    float4 b = *reinterpret_cast<const float4*>(tx + i * DD + lane * 4);
    int s = ids[i];
    float4 c = *reinterpret_cast<const float4*>(Ts + s * DD + lane * 4);
    float dDiag = a.x * b.x + a.y * b.y + a.z * b.z + a.w * b.w;
    float dT    = a.x * tv.x + a.y * tv.y + a.z * tv.z + a.w * tv.w;
    float dTs   = a.x * c.x + a.y * c.y + a.z * c.z + a.w * c.w;
    for (int o = 32; o > 0; o >>= 1) {
      dDiag += __shfl_down(dDiag, o);
      dT    += __shfl_down(dT, o);
      dTs   += __shfl_down(dTs, o);
    }
    if (lane == 0) {
      diag[i] = dDiag;
      int m = counts[s];
      float posMean = (dTs - dDiag) / fmaxf((float)(m - 1), 1.f);
      float negMean = (dT - dTs) / fmaxf((float)(BB - m), 1.f);
      float tri = fmaxf(negMean - posMean + MARGIN, 0.f);
      if (m >= 2 && m <= BB - 1) triAcc += tri;
    }
  }
  if (lane == 0) atomicAdd(&scalars[0], triAcc);
}

// ---- k5: per-species block logsumexp (row & col sum of exp(sim/tau)) ----
// grid (64 species, 8 row-slices), 128 threads (thread = column within chunk)
__global__ void k5_lse(const float* __restrict__ sp, const unsigned int* __restrict__ Th2,
                       const int* __restrict__ counts, const int* __restrict__ offsets,
                       const int* __restrict__ memberList,
                       float* lseRow, float* lseCol) {
  int s = blockIdx.x, r = blockIdx.y;
  int m = counts[s];
  if (m == 0) return;
  int g0 = offsets[s];
  int i0 = (m * r) >> 3, i1 = (m * (r + 1)) >> 3;
  __shared__ unsigned int Ah2[DD2];
  int tid = threadIdx.x;  // 0..127
  for (int jc = 0; jc < m; jc += 128) {
    int j = jc + tid;
    bool active = j < m;
    float colAcc = 0.f;
    for (int i = i0; i < i1; ++i) {
      int mi = memberList[g0 + i];
      __syncthreads();
      float2 v = *reinterpret_cast<const float2*>(sp + mi * DD + 2 * tid);
      Ah2[tid] = pack_h2(v.x, v.y);
      __syncthreads();
      float dA = 0.f, dB = 0.f;
      if (active) {
        const unsigned int* col = Th2 + g0 + j;
        #pragma unroll 8
        for (int d2 = 0; d2 < DD2; d2 += 2) {
          dA = dot2h(Ah2[d2], col[d2 * BB], dA);
          dB = dot2h(Ah2[d2 + 1], col[(d2 + 1) * BB], dB);
        }
      }
      float e = active ? __expf((dA + dB) * (1.f / TAU)) : 0.f;
      colAcc += e;
      float wsum = e;
      for (int o = 32; o > 0; o >>= 1) wsum += __shfl_down(wsum, o);
      if ((tid & 63) == 0) atomicAdd(&lseRow[g0 + i], wsum);
    }
    if (active) atomicAdd(&lseCol[g0 + j], colAcc);
  }
}

// ---- k6: InfoNCE gather: sum over members of (log rowsum + log colsum - 2*diag/tau)/(2m) ----
__global__ void k6_info(const int* __restrict__ memberList, const int* __restrict__ ids,
                        const int* __restrict__ counts, const float* __restrict__ lseRow,
                        const float* __restrict__ lseCol, const float* __restrict__ diag,
                        float* scalars) {
  int g = blockIdx.x * blockDim.x + threadIdx.x;
  float term = 0.f;
  if (g < BB) {
    int i = memberList[g];
    int s = ids[i];
    int m = counts[s];
    if (m >= 2) {
      term = (__logf(lseRow[g]) + __logf(lseCol[g]) - 2.f * diag[i] * (1.f / TAU)) /
             (2.f * (float)m);
    }
  }
  for (int o = 32; o > 0; o >>= 1) term += __shfl_down(term, o);
  if ((threadIdx.x & 63) == 0) atomicAdd(&scalars[1], term);
}

// ---- k7: final combine ----
__global__ void k7_final(const float* __restrict__ scalars, float* out) {
  out[0] = scalars[1] / fmaxf(scalars[2], 1.f) + scalars[0] / fmaxf(scalars[3], 1.f);
}

extern "C" void kernel_launch(void* const* d_in, const int* in_sizes, int n_in,
                              void* d_out, int out_size, void* d_ws, size_t ws_size,
                              hipStream_t stream) {
  const float* sp = (const float*)d_in[0];
  const float* tx = (const float*)d_in[1];
  const int* ids = (const int*)d_in[2];
  float* out = (float*)d_out;

  char* ws = (char*)d_ws;
  float* scalars = (float*)(ws + WS_SCALARS);
  int* counts = (int*)(ws + WS_COUNTS);
  int* offsets = (int*)(ws + WS_OFFSETS);
  float* lseRow = (float*)(ws + WS_LSEROW);
  float* lseCol = (float*)(ws + WS_LSECOL);
  float* diag = (float*)(ws + WS_DIAG);
  int* posin = (int*)(ws + WS_POSIN);
  int* memberList = (int*)(ws + WS_MEMBER);
  float* Ts = (float*)(ws + WS_TS);
  float* T = (float*)(ws + WS_T);
  unsigned int* Th2 = (unsigned int*)(ws + WS_TH2);

  hipMemsetAsync(d_ws, 0, WS_ZERO_BYTES, stream);
  k1_count<<<32, 256, 0, stream>>>(ids, counts, posin);
  k1b_scan<<<1, 64, 0, stream>>>(counts, offsets, scalars);
  k1c_scatter<<<32, 256, 0, stream>>>(ids, posin, offsets, memberList);
  k2_ts<<<NSPEC, 256, 0, stream>>>(tx, counts, offsets, memberList, Ts);
  k2b_t<<<1, 256, 0, stream>>>(Ts, T);
  ktr_transpose<<<BB / 64, 256, 0, stream>>>(tx, memberList, Th2);
  k4_rows<<<256, 256, 0, stream>>>(sp, tx, ids, counts, Ts, T, diag, scalars);
  k5_lse<<<dim3(NSPEC, 8), 128, 0, stream>>>(sp, Th2, counts, offsets, memberList,
                                             lseRow, lseCol);
  k6_info<<<32, 256, 0, stream>>>(memberList, ids, counts, lseRow, lseCol, diag, scalars);
  k7_final<<<1, 1, 0, stream>>>(scalars, out);
}

// Round 2
// 179.096 us; speedup vs baseline: 1.6205x; 1.6205x over previous
//
#include <hip/hip_runtime.h>
#include <hip/hip_fp16.h>

#define TAU 0.07f
#define MARGIN 0.2f
#define NSPEC 64
#define BB 8192
#define DD 256
#define DD2 128  // DD/2

// ---------------- ws layout (bytes) ----------------
// zeroed region: [0, 132096)
//   0      float scalars[8]  [0]=triSum [1]=infoSum [2]=n_valid [3]=n_valid_i
//   32     int   counts[64]
//   288    int   offsets[64]
//   1024   float lseRow[B]
//   33792  float lseCol[B]
//   66560  float Ts[64*256]   (atomic-accumulated)
// unzeroed:
//   132096 float diag[B]
//   164864 int   posin[B]
//   197632 int   memberList[B]
//   230400 float T[256]
//   231424 uint  Th2[128*8192]   (half2-packed, [d2][g] gathered-transposed text)
#define WS_SCALARS   0
#define WS_COUNTS    32
#define WS_OFFSETS   288
#define WS_LSEROW    1024
#define WS_LSECOL    33792
#define WS_TS        66560
#define WS_DIAG      132096
#define WS_POSIN     164864
#define WS_MEMBER    197632
#define WS_T         230400
#define WS_TH2       231424
#define WS_ZERO_BYTES 132096

typedef _Float16 half2v __attribute__((ext_vector_type(2)));

__device__ __forceinline__ float dot2h(unsigned int a, unsigned int b, float c) {
#if __has_builtin(__builtin_amdgcn_fdot2)
  return __builtin_amdgcn_fdot2(__builtin_bit_cast(half2v, a),
                                __builtin_bit_cast(half2v, b), c, false);
#else
  __half2 ha = *reinterpret_cast<const __half2*>(&a);
  __half2 hb = *reinterpret_cast<const __half2*>(&b);
  float2 fa = __half22float2(ha), fb = __half22float2(hb);
  return c + fa.x * fb.x + fa.y * fb.y;
#endif
}

__device__ __forceinline__ unsigned int pack_h2(float x, float y) {
  return (unsigned int)__half_as_ushort(__float2half(x)) |
         ((unsigned int)__half_as_ushort(__float2half(y)) << 16);
}

// ---- k1: species counts + intra-species position ----
__global__ void k1_count(const int* __restrict__ ids, int* counts, int* posin) {
  int i = blockIdx.x * blockDim.x + threadIdx.x;
  if (i < BB) {
    int s = ids[i];
    posin[i] = atomicAdd(&counts[s], 1);
  }
}

// ---- k1b: serial prefix over 64 counts + valid counts ----
__global__ void k1b_scan(const int* __restrict__ counts, int* offsets, float* scalars) {
  if (threadIdx.x == 0) {
    int off = 0, nv = 0, nvi = 0;
    for (int s = 0; s < NSPEC; ++s) {
      offsets[s] = off;
      int c = counts[s];
      off += c;
      if (c >= 2) nv++;
      if (c >= 2 && c <= BB - 1) nvi += c;  // rows with pos_cnt>0 && neg_cnt>0
    }
    scalars[2] = (float)nv;
    scalars[3] = (float)nvi;
  }
}

// ---- k1c: scatter member list (g -> row) ----
__global__ void k1c_scatter(const int* __restrict__ ids, const int* __restrict__ posin,
                            const int* __restrict__ offsets, int* memberList) {
  int i = blockIdx.x * blockDim.x + threadIdx.x;
  if (i < BB) memberList[offsets[ids[i]] + posin[i]] = i;
}

// ---- k2: per-species text sums Ts[s][d], 8 row-slices per species + atomic merge ----
__global__ void k2_ts(const float* __restrict__ tx, const int* __restrict__ counts,
                      const int* __restrict__ offsets, const int* __restrict__ memberList,
                      float* Ts) {
  int s = blockIdx.x, r = blockIdx.y;
  int m = counts[s], g0 = offsets[s];
  int k0 = (m * r) >> 3, k1 = (m * (r + 1)) >> 3;
  if (k0 >= k1) return;
  int d = threadIdx.x;
  float acc = 0.f;
  for (int k = k0; k < k1; ++k) acc += tx[memberList[g0 + k] * DD + d];
  atomicAdd(&Ts[s * DD + d], acc);
}

// ---- k2b: global text sum T[d] ----
__global__ void k2b_t(const float* __restrict__ Ts, float* T) {
  int d = threadIdx.x;
  float acc = 0.f;
  for (int s = 0; s < NSPEC; ++s) acc += Ts[s * DD + d];
  T[d] = acc;
}

// ---- ktr: gathered transpose of text into half2 [d2][g] layout ----
__global__ void ktr_transpose(const float* __restrict__ tx, const int* __restrict__ memberList,
                              unsigned int* __restrict__ Th2) {
  __shared__ unsigned int tile[64][129];  // +1 dword pad: conflict-free both phases
  int g0 = blockIdx.x * 64;
  int half = threadIdx.x >> 7;   // 0/1: two member rows per iteration
  int d2 = threadIdx.x & 127;
  for (int k = 0; k < 64; k += 2) {
    int kk = k + half;
    int row = memberList[g0 + kk];
    float2 v = *reinterpret_cast<const float2*>(tx + row * DD + 2 * d2);
    tile[kk][d2] = pack_h2(v.x, v.y);
  }
  __syncthreads();
  for (int it = 0; it < 32; ++it) {
    int flat = it * 256 + threadIdx.x;
    int dd = flat >> 6;    // 0..127
    int g = flat & 63;
    Th2[dd * BB + g0 + g] = tile[g][dd];  // coalesced 256B per wave
  }
}

// ---- k4: diag, row_sum, row_same_sum -> triplet accumulation; writes diag ----
__global__ void k4_rows(const float* __restrict__ sp, const float* __restrict__ tx,
                        const int* __restrict__ ids, const int* __restrict__ counts,
                        const float* __restrict__ Ts, const float* __restrict__ T,
                        float* diag, float* scalars) {
  int tid = blockIdx.x * blockDim.x + threadIdx.x;
  int w = tid >> 6, lane = tid & 63;
  const int NW = (512 * 256) >> 6;  // 2048 waves
  float4 tv = *reinterpret_cast<const float4*>(T + lane * 4);
  float triAcc = 0.f;
  for (int i = w; i < BB; i += NW) {
    float4 a = *reinterpret_cast<const float4*>(sp + i * DD + lane * 4);
    float4 b = *reinterpret_cast<const float4*>(tx + i * DD + lane * 4);
    int s = ids[i];
    float4 c = *reinterpret_cast<const float4*>(Ts + s * DD + lane * 4);
    float dDiag = a.x * b.x + a.y * b.y + a.z * b.z + a.w * b.w;
    float dT    = a.x * tv.x + a.y * tv.y + a.z * tv.z + a.w * tv.w;
    float dTs   = a.x * c.x + a.y * c.y + a.z * c.z + a.w * c.w;
    for (int o = 32; o > 0; o >>= 1) {
      dDiag += __shfl_down(dDiag, o);
      dT    += __shfl_down(dT, o);
      dTs   += __shfl_down(dTs, o);
    }
    if (lane == 0) {
      diag[i] = dDiag;
      int m = counts[s];
      float posMean = (dTs - dDiag) / fmaxf((float)(m - 1), 1.f);
      float negMean = (dT - dTs) / fmaxf((float)(BB - m), 1.f);
      float tri = fmaxf(negMean - posMean + MARGIN, 0.f);
      if (m >= 2 && m <= BB - 1) triAcc += tri;
    }
  }
  if (lane == 0) atomicAdd(&scalars[0], triAcc);
}

// ---- k5: per-species block sum-of-exp, register-tiled ----
// grid (64 species, 16 row-slices), 256 threads. Stage 8 A-rows in LDS once,
// each thread owns one column, keeps 8 row-accumulators in registers:
// every column element is loaded once and reused 8x.
__global__ void k5_lse(const float* __restrict__ sp, const unsigned int* __restrict__ Th2,
                       const int* __restrict__ counts, const int* __restrict__ offsets,
                       const int* __restrict__ memberList,
                       float* lseRow, float* lseCol) {
  int s = blockIdx.x, r = blockIdx.y;
  int m = counts[s];
  if (m == 0) return;
  int g0 = offsets[s];
  int i0 = (m * r) >> 4, i1 = (m * (r + 1)) >> 4;
  __shared__ unsigned int A[8][DD2];   // 8 rows x 128 half2-packed dwords (4 KB)
  int tid = threadIdx.x;  // 0..255

  for (int ib = i0; ib < i1; ib += 8) {
    int nr = min(8, i1 - ib);
    __syncthreads();
    // stage nr rows: 8*128 = 1024 dwords by 256 threads in 4 steps
    #pragma unroll
    for (int p = 0; p < 4; ++p) {
      int flat = p * 256 + tid;
      int row = flat >> 7;       // 0..7
      int d2 = flat & 127;
      int rr = row < nr ? row : nr - 1;   // clamp: stage valid data, results unused
      int mi = memberList[g0 + ib + rr];
      float2 v = *reinterpret_cast<const float2*>(sp + mi * DD + 2 * d2);
      A[row][d2] = pack_h2(v.x, v.y);
    }
    __syncthreads();

    for (int jc = 0; jc < m; jc += 256) {
      int j = jc + tid;
      bool act = j < m;
      float acc[8];
      #pragma unroll
      for (int q = 0; q < 8; ++q) acc[q] = 0.f;
      if (act) {
        const unsigned int* colb = Th2 + g0 + j;
        #pragma unroll 4
        for (int d2g = 0; d2g < 32; ++d2g) {
          unsigned int c0 = colb[(d2g * 4 + 0) * BB];
          unsigned int c1 = colb[(d2g * 4 + 1) * BB];
          unsigned int c2 = colb[(d2g * 4 + 2) * BB];
          unsigned int c3 = colb[(d2g * 4 + 3) * BB];
          #pragma unroll
          for (int q = 0; q < 8; ++q) {
            uint4 a = *reinterpret_cast<const uint4*>(&A[q][d2g * 4]);
            acc[q] = dot2h(a.w, c3, dot2h(a.z, c2, dot2h(a.y, c1, dot2h(a.x, c0, acc[q]))));
          }
        }
      }
      float colAcc = 0.f;
      #pragma unroll
      for (int q = 0; q < 8; ++q) {
        bool rv = q < nr;
        float e = (act && rv) ? __expf(acc[q] * (1.f / TAU)) : 0.f;
        colAcc += e;
        float w = e;
        for (int o = 32; o > 0; o >>= 1) w += __shfl_down(w, o);
        if ((tid & 63) == 0 && rv) atomicAdd(&lseRow[g0 + ib + q], w);
      }
      if (act) atomicAdd(&lseCol[g0 + j], colAcc);
    }
  }
}

// ---- k6: InfoNCE gather ----
__global__ void k6_info(const int* __restrict__ memberList, const int* __restrict__ ids,
                        const int* __restrict__ counts, const float* __restrict__ lseRow,
                        const float* __restrict__ lseCol, const float* __restrict__ diag,
                        float* scalars) {
  int g = blockIdx.x * blockDim.x + threadIdx.x;
  float term = 0.f;
  if (g < BB) {
    int i = memberList[g];
    int s = ids[i];
    int m = counts[s];
    if (m >= 2) {
      term = (__logf(lseRow[g]) + __logf(lseCol[g]) - 2.f * diag[i] * (1.f / TAU)) /
             (2.f * (float)m);
    }
  }
  for (int o = 32; o > 0; o >>= 1) term += __shfl_down(term, o);
  if ((threadIdx.x & 63) == 0) atomicAdd(&scalars[1], term);
}

// ---- k7: final combine ----
__global__ void k7_final(const float* __restrict__ scalars, float* out) {
  out[0] = scalars[1] / fmaxf(scalars[2], 1.f) + scalars[0] / fmaxf(scalars[3], 1.f);
}

extern "C" void kernel_launch(void* const* d_in, const int* in_sizes, int n_in,
                              void* d_out, int out_size, void* d_ws, size_t ws_size,
                              hipStream_t stream) {
  const float* sp = (const float*)d_in[0];
  const float* tx = (const float*)d_in[1];
  const int* ids = (const int*)d_in[2];
  float* out = (float*)d_out;

  char* ws = (char*)d_ws;
  float* scalars = (float*)(ws + WS_SCALARS);
  int* counts = (int*)(ws + WS_COUNTS);
  int* offsets = (int*)(ws + WS_OFFSETS);
  float* lseRow = (float*)(ws + WS_LSEROW);
  float* lseCol = (float*)(ws + WS_LSECOL);
  float* Ts = (float*)(ws + WS_TS);
  float* diag = (float*)(ws + WS_DIAG);
  int* posin = (int*)(ws + WS_POSIN);
  int* memberList = (int*)(ws + WS_MEMBER);
  float* T = (float*)(ws + WS_T);
  unsigned int* Th2 = (unsigned int*)(ws + WS_TH2);

  hipMemsetAsync(d_ws, 0, WS_ZERO_BYTES, stream);
  k1_count<<<32, 256, 0, stream>>>(ids, counts, posin);
  k1b_scan<<<1, 64, 0, stream>>>(counts, offsets, scalars);
  k1c_scatter<<<32, 256, 0, stream>>>(ids, posin, offsets, memberList);
  k2_ts<<<dim3(NSPEC, 8), 256, 0, stream>>>(tx, counts, offsets, memberList, Ts);
  k2b_t<<<1, 256, 0, stream>>>(Ts, T);
  ktr_transpose<<<BB / 64, 256, 0, stream>>>(tx, memberList, Th2);
  k4_rows<<<512, 256, 0, stream>>>(sp, tx, ids, counts, Ts, T, diag, scalars);
  k5_lse<<<dim3(NSPEC, 16), 256, 0, stream>>>(sp, Th2, counts, offsets, memberList,
                                              lseRow, lseCol);
  k6_info<<<32, 256, 0, stream>>>(memberList, ids, counts, lseRow, lseCol, diag, scalars);
  k7_final<<<1, 1, 0, stream>>>(scalars, out);
}

// Round 3
// 157.232 us; speedup vs baseline: 1.8459x; 1.1391x over previous
//
#include <hip/hip_runtime.h>
#include <hip/hip_fp16.h>

#define TAU 0.07f
#define MARGIN 0.2f
#define NSPEC 64
#define BB 8192
#define DD 256

// ---------------- ws layout (bytes) ----------------
// zeroed region: [0, 132096)
//   0      float scalars[8]  [1]=infoSum [2]=n_valid [3]=n_valid_i
//   32     float triBuckets[64]
//   288    int   counts[64]
//   544    int   offsets[64]
//   1024   float lseRow[B]
//   33792  float lseCol[B]
//   66560  float Ts[64*256]   (atomic-accumulated)
// unzeroed:
//   132096 float diag[B]
//   164864 int   memberList[B]
//   197632 float T[256]
#define WS_SCALARS   0
#define WS_TRIB      32
#define WS_COUNTS    288
#define WS_OFFSETS   544
#define WS_LSEROW    1024
#define WS_LSECOL    33792
#define WS_TS        66560
#define WS_DIAG      132096
#define WS_MEMBER    164864
#define WS_T         197632
#define WS_ZERO_BYTES 132096

typedef _Float16 half8 __attribute__((ext_vector_type(8)));
typedef float float4v __attribute__((ext_vector_type(4)));
typedef unsigned int uint4v __attribute__((ext_vector_type(4)));

__device__ __forceinline__ uint4v pack8(float4 a, float4 b) {
  half8 h;
  h[0] = (_Float16)a.x; h[1] = (_Float16)a.y; h[2] = (_Float16)a.z; h[3] = (_Float16)a.w;
  h[4] = (_Float16)b.x; h[5] = (_Float16)b.y; h[6] = (_Float16)b.z; h[7] = (_Float16)b.w;
  return __builtin_bit_cast(uint4v, h);
}

// ---- k1_all: counts + scan + scatter + valid-counts, single block 1024 thr ----
__global__ void k1_all(const int* __restrict__ ids, int* counts_g, int* offsets_g,
                       int* memberList, float* scalars) {
  __shared__ int cnt[NSPEC];
  __shared__ int off[NSPEC];
  int tid = threadIdx.x;
  if (tid < NSPEC) cnt[tid] = 0;
  __syncthreads();
  int myS[8], myP[8];
  #pragma unroll
  for (int r = 0; r < 8; ++r) {
    int i = r * 1024 + tid;
    int s = ids[i];
    myS[r] = s;
    myP[r] = atomicAdd(&cnt[s], 1);
  }
  __syncthreads();
  if (tid < NSPEC) {  // exactly wave 0
    int o = 0;
    for (int t = 0; t < NSPEC; ++t) o += (t < tid) ? cnt[t] : 0;
    off[tid] = o;
    offsets_g[tid] = o;
    int c = cnt[tid];
    counts_g[tid] = c;
    unsigned long long bv = __ballot(c >= 2);
    float nvi = (c >= 2 && c <= BB - 1) ? (float)c : 0.f;
    for (int o2 = 1; o2 < 64; o2 <<= 1) nvi += __shfl_xor(nvi, o2);
    if (tid == 0) {
      scalars[2] = (float)__popcll(bv);
      scalars[3] = nvi;
    }
  }
  __syncthreads();
  #pragma unroll
  for (int r = 0; r < 8; ++r) {
    int i = r * 1024 + tid;
    memberList[off[myS[r]] + myP[r]] = i;
  }
}

// ---- k2: per-species text sums Ts[s][d], 8 row-slices per species + atomic merge ----
__global__ void k2_ts(const float* __restrict__ tx, const int* __restrict__ counts,
                      const int* __restrict__ offsets, const int* __restrict__ memberList,
                      float* Ts) {
  int s = blockIdx.x, r = blockIdx.y;
  int m = counts[s], g0 = offsets[s];
  int k0 = (m * r) >> 3, k1 = (m * (r + 1)) >> 3;
  if (k0 >= k1) return;
  int d = threadIdx.x;
  float acc = 0.f;
  for (int k = k0; k < k1; ++k) acc += tx[memberList[g0 + k] * DD + d];
  atomicAdd(&Ts[s * DD + d], acc);
}

// ---- k2b: global text sum T[d] ----
__global__ void k2b_t(const float* __restrict__ Ts, float* T) {
  int d = threadIdx.x;
  float acc = 0.f;
  for (int s = 0; s < NSPEC; ++s) acc += Ts[s * DD + d];
  T[d] = acc;
}

// ---- k4: one wave per row: diag + triplet; bucketed scalar atomics ----
__global__ void k4_rows(const float* __restrict__ sp, const float* __restrict__ tx,
                        const int* __restrict__ ids, const int* __restrict__ counts,
                        const float* __restrict__ Ts, const float* __restrict__ T,
                        float* diag, float* triBuckets) {
  int gt = blockIdx.x * 256 + threadIdx.x;
  int i = gt >> 6, lane = gt & 63;
  float4 a = *reinterpret_cast<const float4*>(sp + i * DD + lane * 4);
  float4 b = *reinterpret_cast<const float4*>(tx + i * DD + lane * 4);
  float4 tv = *reinterpret_cast<const float4*>(T + lane * 4);
  int s = ids[i];
  int m = counts[s];
  float4 c = *reinterpret_cast<const float4*>(Ts + s * DD + lane * 4);
  float dDiag = a.x * b.x + a.y * b.y + a.z * b.z + a.w * b.w;
  float dT    = a.x * tv.x + a.y * tv.y + a.z * tv.z + a.w * tv.w;
  float dTs   = a.x * c.x + a.y * c.y + a.z * c.z + a.w * c.w;
  #pragma unroll
  for (int o = 1; o < 64; o <<= 1) {
    dDiag += __shfl_xor(dDiag, o);
    dT    += __shfl_xor(dT, o);
    dTs   += __shfl_xor(dTs, o);
  }
  if (lane == 0) {
    diag[i] = dDiag;
    float posMean = (dTs - dDiag) / fmaxf((float)(m - 1), 1.f);
    float negMean = (dT - dTs) / fmaxf((float)(BB - m), 1.f);
    float tri = fmaxf(negMean - posMean + MARGIN, 0.f);
    if (m >= 2 && m <= BB - 1) atomicAdd(&triBuckets[i & 63], tri);
  }
}

// ---- k5: per-species masked sum-of-exp via MFMA f16 ----
// Block tile: 64 rows x 128 cols; K=256 in 4 chunks of 64.
// LDS fragment-order: 16B unit (ksl, row, quad) = row's d[kc*64+ksl*32+quad*8 .. +8) as f16.
__global__ void k5_lse(const float* __restrict__ sp, const float* __restrict__ tx,
                       const int* __restrict__ counts, const int* __restrict__ offsets,
                       const int* __restrict__ memberList,
                       float* lseRow, float* lseCol) {
  __shared__ uint4v lds5[1536];  // A: [0,512) = 2*64*4 units; B: [512,1536) = 2*128*4
  int s = blockIdx.x;
  int m = counts[s];
  int g0 = offsets[s];
  int tid = threadIdx.x;
  int lane = tid & 63, wv = tid >> 6;
  int quad = lane >> 4, cl = lane & 15;

  for (int rt = blockIdx.y; rt * 64 < m; rt += gridDim.y) {
    for (int ct = blockIdx.z; ct * 128 < m; ct += gridDim.z) {
      float4v acc[8];
      #pragma unroll
      for (int cf = 0; cf < 8; ++cf) acc[cf] = (float4v){0.f, 0.f, 0.f, 0.f};

      for (int kc = 0; kc < 4; ++kc) {
        __syncthreads();
        // stage 1536 units, 6 per thread
        #pragma unroll
        for (int p = 0; p < 6; ++p) {
          int u = p * 256 + tid;
          int isB = u >= 512;
          int v = isB ? (u - 512) : u;
          int row = v >> 3;            // A: 0..63 ; B: 0..127
          int sub = v & 7;
          int ksl = sub >> 2, q = sub & 3;
          int d0 = kc * 64 + ksl * 32 + q * 8;
          int idx = isB ? (ct * 128 + row) : (rt * 64 + row);
          uint4v val = (uint4v){0u, 0u, 0u, 0u};
          if (idx < m) {
            const float* src = (isB ? tx : sp) + memberList[g0 + idx] * DD + d0;
            float4 f0 = *reinterpret_cast<const float4*>(src);
            float4 f1 = *reinterpret_cast<const float4*>(src + 4);
            val = pack8(f0, f1);
          }
          int dst = isB ? (512 + (ksl * 128 + row) * 4 + q)
                        : ((ksl * 64 + row) * 4 + q);
          lds5[dst] = val;
        }
        __syncthreads();
        #pragma unroll
        for (int ksl = 0; ksl < 2; ++ksl) {
          half8 a = __builtin_bit_cast(half8, lds5[(ksl * 64 + wv * 16 + cl) * 4 + quad]);
          #pragma unroll
          for (int cf = 0; cf < 8; ++cf) {
            half8 b = __builtin_bit_cast(half8, lds5[512 + (ksl * 128 + cf * 16 + cl) * 4 + quad]);
            acc[cf] = __builtin_amdgcn_mfma_f32_16x16x32_f16(a, b, acc[cf], 0, 0, 0);
          }
        }
      }

      // epilogue: masked exp, row/col sums
      int riBase = rt * 64 + wv * 16 + quad * 4;  // + reg
      float rowAcc[4] = {0.f, 0.f, 0.f, 0.f};
      #pragma unroll
      for (int cf = 0; cf < 8; ++cf) {
        int ci = ct * 128 + cf * 16 + cl;
        bool cv = ci < m;
        float colAcc = 0.f;
        #pragma unroll
        for (int reg = 0; reg < 4; ++reg) {
          bool rv = (riBase + reg) < m;
          float e = (rv && cv) ? __expf(acc[cf][reg] * (1.f / TAU)) : 0.f;
          rowAcc[reg] += e;
          colAcc += e;
        }
        colAcc += __shfl_xor(colAcc, 16);
        colAcc += __shfl_xor(colAcc, 32);
        if (quad == 0 && cv) atomicAdd(&lseCol[g0 + ci], colAcc);
      }
      #pragma unroll
      for (int reg = 0; reg < 4; ++reg) {
        float v = rowAcc[reg];
        v += __shfl_xor(v, 1);
        v += __shfl_xor(v, 2);
        v += __shfl_xor(v, 4);
        v += __shfl_xor(v, 8);
        if (cl == 0 && (riBase + reg) < m) atomicAdd(&lseRow[g0 + riBase + reg], v);
      }
    }
  }
}

// ---- k6: InfoNCE gather ----
__global__ void k6_info(const int* __restrict__ memberList, const int* __restrict__ ids,
                        const int* __restrict__ counts, const float* __restrict__ lseRow,
                        const float* __restrict__ lseCol, const float* __restrict__ diag,
                        float* scalars) {
  int g = blockIdx.x * blockDim.x + threadIdx.x;
  float term = 0.f;
  if (g < BB) {
    int i = memberList[g];
    int s = ids[i];
    int m = counts[s];
    if (m >= 2) {
      term = (__logf(lseRow[g]) + __logf(lseCol[g]) - 2.f * diag[i] * (1.f / TAU)) /
             (2.f * (float)m);
    }
  }
  for (int o = 32; o > 0; o >>= 1) term += __shfl_down(term, o);
  if ((threadIdx.x & 63) == 0) atomicAdd(&scalars[1], term);
}

// ---- k7: final combine (sums tri buckets) ----
__global__ void k7_final(const float* __restrict__ scalars,
                         const float* __restrict__ triBuckets, float* out) {
  int lane = threadIdx.x;  // 64
  float t = triBuckets[lane];
  for (int o = 1; o < 64; o <<= 1) t += __shfl_xor(t, o);
  if (lane == 0)
    out[0] = scalars[1] / fmaxf(scalars[2], 1.f) + t / fmaxf(scalars[3], 1.f);
}

extern "C" void kernel_launch(void* const* d_in, const int* in_sizes, int n_in,
                              void* d_out, int out_size, void* d_ws, size_t ws_size,
                              hipStream_t stream) {
  const float* sp = (const float*)d_in[0];
  const float* tx = (const float*)d_in[1];
  const int* ids = (const int*)d_in[2];
  float* out = (float*)d_out;

  char* ws = (char*)d_ws;
  float* scalars = (float*)(ws + WS_SCALARS);
  float* triBuckets = (float*)(ws + WS_TRIB);
  int* counts = (int*)(ws + WS_COUNTS);
  int* offsets = (int*)(ws + WS_OFFSETS);
  float* lseRow = (float*)(ws + WS_LSEROW);
  float* lseCol = (float*)(ws + WS_LSECOL);
  float* Ts = (float*)(ws + WS_TS);
  float* diag = (float*)(ws + WS_DIAG);
  int* memberList = (int*)(ws + WS_MEMBER);
  float* T = (float*)(ws + WS_T);

  hipMemsetAsync(d_ws, 0, WS_ZERO_BYTES, stream);
  k1_all<<<1, 1024, 0, stream>>>(ids, counts, offsets, memberList, scalars);
  k2_ts<<<dim3(NSPEC, 8), 256, 0, stream>>>(tx, counts, offsets, memberList, Ts);
  k2b_t<<<1, 256, 0, stream>>>(Ts, T);
  k4_rows<<<BB / 4, 256, 0, stream>>>(sp, tx, ids, counts, Ts, T, diag, triBuckets);
  k5_lse<<<dim3(NSPEC, 4, 2), 256, 0, stream>>>(sp, tx, counts, offsets, memberList,
                                                lseRow, lseCol);
  k6_info<<<32, 256, 0, stream>>>(memberList, ids, counts, lseRow, lseCol, diag, scalars);
  k7_final<<<1, 64, 0, stream>>>(scalars, triBuckets, out);
}

// Round 4
// 111.041 us; speedup vs baseline: 2.6137x; 1.4160x over previous
//
#include <hip/hip_runtime.h>
#include <hip/hip_fp16.h>

#define TAU 0.07f
#define MARGIN 0.2f
#define NSPEC 64
#define BB 8192
#define DD 256

// ---------------- ws layout (bytes) ----------------
// zeroed region: [0, 132096)
//   0      float scalars[8]  [0]=triSum [1]=infoSum [2]=n_valid [3]=n_valid_i
//   288    int   counts[64]
//   544    int   offsets[64]
//   1024   float lseRow[B]
//   33792  float lseCol[B]
//   66560  float Ts[64*256]   (atomic-accumulated)
// unzeroed:
//   132096 float diag[B]
//   164864 int   memberList[B]
//   197632 float T[256]
//   198656 float tri[B]
#define WS_SCALARS   0
#define WS_COUNTS    288
#define WS_OFFSETS   544
#define WS_LSEROW    1024
#define WS_LSECOL    33792
#define WS_TS        66560
#define WS_DIAG      132096
#define WS_MEMBER    164864
#define WS_T         197632
#define WS_TRI       198656
#define WS_ZERO_BYTES 132096

typedef _Float16 half8 __attribute__((ext_vector_type(8)));
typedef float float4v __attribute__((ext_vector_type(4)));
typedef unsigned int uint4v __attribute__((ext_vector_type(4)));

__device__ __forceinline__ uint4v pack8(float4 a, float4 b) {
  half8 h;
  h[0] = (_Float16)a.x; h[1] = (_Float16)a.y; h[2] = (_Float16)a.z; h[3] = (_Float16)a.w;
  h[4] = (_Float16)b.x; h[5] = (_Float16)b.y; h[6] = (_Float16)b.z; h[7] = (_Float16)b.w;
  return __builtin_bit_cast(uint4v, h);
}

// ---- k1_all: counts + scan + scatter + valid-counts, single block 1024 thr ----
__global__ void k1_all(const int* __restrict__ ids, int* counts_g, int* offsets_g,
                       int* memberList, float* scalars) {
  __shared__ int cnt[NSPEC];
  __shared__ int off[NSPEC];
  int tid = threadIdx.x;
  if (tid < NSPEC) cnt[tid] = 0;
  __syncthreads();
  int myS[8], myP[8];
  #pragma unroll
  for (int r = 0; r < 8; ++r) {
    int i = r * 1024 + tid;
    int s = ids[i];
    myS[r] = s;
    myP[r] = atomicAdd(&cnt[s], 1);
  }
  __syncthreads();
  if (tid < NSPEC) {  // exactly wave 0
    int o = 0;
    for (int t = 0; t < NSPEC; ++t) o += (t < tid) ? cnt[t] : 0;
    off[tid] = o;
    offsets_g[tid] = o;
    int c = cnt[tid];
    counts_g[tid] = c;
    unsigned long long bv = __ballot(c >= 2);
    float nvi = (c >= 2 && c <= BB - 1) ? (float)c : 0.f;
    for (int o2 = 1; o2 < 64; o2 <<= 1) nvi += __shfl_xor(nvi, o2);
    if (tid == 0) {
      scalars[2] = (float)__popcll(bv);
      scalars[3] = nvi;
    }
  }
  __syncthreads();
  #pragma unroll
  for (int r = 0; r < 8; ++r) {
    int i = r * 1024 + tid;
    memberList[off[myS[r]] + myP[r]] = i;
  }
}

// ---- k2: per-species text sums Ts[s][d], 8 row-slices per species + atomic merge ----
__global__ void k2_ts(const float* __restrict__ tx, const int* __restrict__ counts,
                      const int* __restrict__ offsets, const int* __restrict__ memberList,
                      float* Ts) {
  int s = blockIdx.x, r = blockIdx.y;
  int m = counts[s], g0 = offsets[s];
  int k0 = (m * r) >> 3, k1 = (m * (r + 1)) >> 3;
  if (k0 >= k1) return;
  int d = threadIdx.x;
  float acc = 0.f;
  for (int k = k0; k < k1; ++k) acc += tx[memberList[g0 + k] * DD + d];
  atomicAdd(&Ts[s * DD + d], acc);
}

// ---- k2b: global text sum T[d] ----
__global__ void k2b_t(const float* __restrict__ Ts, float* T) {
  int d = threadIdx.x;
  float acc = 0.f;
  for (int s = 0; s < NSPEC; ++s) acc += Ts[s * DD + d];
  T[d] = acc;
}

// ---- k4: one wave per row: diag + triplet; NO atomics (plain stores) ----
__global__ void k4_rows(const float* __restrict__ sp, const float* __restrict__ tx,
                        const int* __restrict__ ids, const int* __restrict__ counts,
                        const float* __restrict__ Ts, const float* __restrict__ T,
                        float* diag, float* tri) {
  int gt = blockIdx.x * 256 + threadIdx.x;
  int i = gt >> 6, lane = gt & 63;
  float4 a = *reinterpret_cast<const float4*>(sp + i * DD + lane * 4);
  float4 b = *reinterpret_cast<const float4*>(tx + i * DD + lane * 4);
  float4 tv = *reinterpret_cast<const float4*>(T + lane * 4);
  int s = ids[i];
  int m = counts[s];
  float4 c = *reinterpret_cast<const float4*>(Ts + s * DD + lane * 4);
  float dDiag = a.x * b.x + a.y * b.y + a.z * b.z + a.w * b.w;
  float dT    = a.x * tv.x + a.y * tv.y + a.z * tv.z + a.w * tv.w;
  float dTs   = a.x * c.x + a.y * c.y + a.z * c.z + a.w * c.w;
  #pragma unroll
  for (int o = 1; o < 64; o <<= 1) {
    dDiag += __shfl_xor(dDiag, o);
    dT    += __shfl_xor(dT, o);
    dTs   += __shfl_xor(dTs, o);
  }
  if (lane == 0) {
    diag[i] = dDiag;
    float posMean = (dTs - dDiag) / fmaxf((float)(m - 1), 1.f);
    float negMean = (dT - dTs) / fmaxf((float)(BB - m), 1.f);
    float t = fmaxf(negMean - posMean + MARGIN, 0.f);
    tri[i] = (m >= 2 && m <= BB - 1) ? t : 0.f;
  }
}

// ---- k5: per-species masked sum-of-exp via MFMA f16 ----
// Block tile: 64 rows x 128 cols; K=256 in 4 chunks of 64.
// LDS fragment-order: 16B unit (ksl, row, quad) = row's d[kc*64+ksl*32+quad*8 .. +8) as f16.
__global__ void k5_lse(const float* __restrict__ sp, const float* __restrict__ tx,
                       const int* __restrict__ counts, const int* __restrict__ offsets,
                       const int* __restrict__ memberList,
                       float* lseRow, float* lseCol) {
  __shared__ uint4v lds5[1536];  // A: [0,512) = 2*64*4 units; B: [512,1536) = 2*128*4
  int s = blockIdx.x;
  int m = counts[s];
  int g0 = offsets[s];
  int tid = threadIdx.x;
  int lane = tid & 63, wv = tid >> 6;
  int quad = lane >> 4, cl = lane & 15;

  for (int rt = blockIdx.y; rt * 64 < m; rt += gridDim.y) {
    for (int ct = blockIdx.z; ct * 128 < m; ct += gridDim.z) {
      float4v acc[8];
      #pragma unroll
      for (int cf = 0; cf < 8; ++cf) acc[cf] = (float4v){0.f, 0.f, 0.f, 0.f};

      for (int kc = 0; kc < 4; ++kc) {
        __syncthreads();
        // stage 1536 units, 6 per thread
        #pragma unroll
        for (int p = 0; p < 6; ++p) {
          int u = p * 256 + tid;
          int isB = u >= 512;
          int v = isB ? (u - 512) : u;
          int row = v >> 3;            // A: 0..63 ; B: 0..127
          int sub = v & 7;
          int ksl = sub >> 2, q = sub & 3;
          int d0 = kc * 64 + ksl * 32 + q * 8;
          int idx = isB ? (ct * 128 + row) : (rt * 64 + row);
          uint4v val = (uint4v){0u, 0u, 0u, 0u};
          if (idx < m) {
            const float* src = (isB ? tx : sp) + memberList[g0 + idx] * DD + d0;
            float4 f0 = *reinterpret_cast<const float4*>(src);
            float4 f1 = *reinterpret_cast<const float4*>(src + 4);
            val = pack8(f0, f1);
          }
          int dst = isB ? (512 + (ksl * 128 + row) * 4 + q)
                        : ((ksl * 64 + row) * 4 + q);
          lds5[dst] = val;
        }
        __syncthreads();
        #pragma unroll
        for (int ksl = 0; ksl < 2; ++ksl) {
          half8 a = __builtin_bit_cast(half8, lds5[(ksl * 64 + wv * 16 + cl) * 4 + quad]);
          #pragma unroll
          for (int cf = 0; cf < 8; ++cf) {
            half8 b = __builtin_bit_cast(half8, lds5[512 + (ksl * 128 + cf * 16 + cl) * 4 + quad]);
            acc[cf] = __builtin_amdgcn_mfma_f32_16x16x32_f16(a, b, acc[cf], 0, 0, 0);
          }
        }
      }

      // epilogue: masked exp, row/col sums
      int riBase = rt * 64 + wv * 16 + quad * 4;  // + reg
      float rowAcc[4] = {0.f, 0.f, 0.f, 0.f};
      #pragma unroll
      for (int cf = 0; cf < 8; ++cf) {
        int ci = ct * 128 + cf * 16 + cl;
        bool cv = ci < m;
        float colAcc = 0.f;
        #pragma unroll
        for (int reg = 0; reg < 4; ++reg) {
          bool rv = (riBase + reg) < m;
          float e = (rv && cv) ? __expf(acc[cf][reg] * (1.f / TAU)) : 0.f;
          rowAcc[reg] += e;
          colAcc += e;
        }
        colAcc += __shfl_xor(colAcc, 16);
        colAcc += __shfl_xor(colAcc, 32);
        if (quad == 0 && cv) atomicAdd(&lseCol[g0 + ci], colAcc);
      }
      #pragma unroll
      for (int reg = 0; reg < 4; ++reg) {
        float v = rowAcc[reg];
        v += __shfl_xor(v, 1);
        v += __shfl_xor(v, 2);
        v += __shfl_xor(v, 4);
        v += __shfl_xor(v, 8);
        if (cl == 0 && (riBase + reg) < m) atomicAdd(&lseRow[g0 + riBase + reg], v);
      }
    }
  }
}

// ---- k6: InfoNCE gather + tri reduction; one atomic pair per block ----
__global__ void k6_info(const int* __restrict__ memberList, const int* __restrict__ ids,
                        const int* __restrict__ counts, const float* __restrict__ lseRow,
                        const float* __restrict__ lseCol, const float* __restrict__ diag,
                        const float* __restrict__ tri, float* scalars) {
  __shared__ float red[8];  // [0..3]=info per wave, [4..7]=tri per wave
  int g = blockIdx.x * blockDim.x + threadIdx.x;
  int i = memberList[g];
  int s = ids[i];
  int m = counts[s];
  float tt = tri[i];
  float term = 0.f;
  if (m >= 2) {
    term = (__logf(lseRow[g]) + __logf(lseCol[g]) - 2.f * diag[i] * (1.f / TAU)) /
           (2.f * (float)m);
  }
  #pragma unroll
  for (int o = 1; o < 64; o <<= 1) {
    term += __shfl_xor(term, o);
    tt += __shfl_xor(tt, o);
  }
  int wv = threadIdx.x >> 6, lane = threadIdx.x & 63;
  if (lane == 0) { red[wv] = term; red[4 + wv] = tt; }
  __syncthreads();
  if (threadIdx.x == 0) {
    atomicAdd(&scalars[1], red[0] + red[1] + red[2] + red[3]);
    atomicAdd(&scalars[0], red[4] + red[5] + red[6] + red[7]);
  }
}

// ---- k7: final combine ----
__global__ void k7_final(const float* __restrict__ scalars, float* out) {
  out[0] = scalars[1] / fmaxf(scalars[2], 1.f) + scalars[0] / fmaxf(scalars[3], 1.f);
}

extern "C" void kernel_launch(void* const* d_in, const int* in_sizes, int n_in,
                              void* d_out, int out_size, void* d_ws, size_t ws_size,
                              hipStream_t stream) {
  const float* sp = (const float*)d_in[0];
  const float* tx = (const float*)d_in[1];
  const int* ids = (const int*)d_in[2];
  float* out = (float*)d_out;

  char* ws = (char*)d_ws;
  float* scalars = (float*)(ws + WS_SCALARS);
  int* counts = (int*)(ws + WS_COUNTS);
  int* offsets = (int*)(ws + WS_OFFSETS);
  float* lseRow = (float*)(ws + WS_LSEROW);
  float* lseCol = (float*)(ws + WS_LSECOL);
  float* Ts = (float*)(ws + WS_TS);
  float* diag = (float*)(ws + WS_DIAG);
  int* memberList = (int*)(ws + WS_MEMBER);
  float* T = (float*)(ws + WS_T);
  float* tri = (float*)(ws + WS_TRI);

  hipMemsetAsync(d_ws, 0, WS_ZERO_BYTES, stream);
  k1_all<<<1, 1024, 0, stream>>>(ids, counts, offsets, memberList, scalars);
  k2_ts<<<dim3(NSPEC, 8), 256, 0, stream>>>(tx, counts, offsets, memberList, Ts);
  k2b_t<<<1, 256, 0, stream>>>(Ts, T);
  k4_rows<<<BB / 4, 256, 0, stream>>>(sp, tx, ids, counts, Ts, T, diag, tri);
  k5_lse<<<dim3(NSPEC, 4, 2), 256, 0, stream>>>(sp, tx, counts, offsets, memberList,
                                                lseRow, lseCol);
  k6_info<<<32, 256, 0, stream>>>(memberList, ids, counts, lseRow, lseCol, diag, tri,
                                  scalars);
  k7_final<<<1, 1, 0, stream>>>(scalars, out);
}